// Round 1
// baseline (103.733 us; speedup 1.0000x reference)
//
#include <hip/hip_runtime.h>

// out[b,p,o] = sum_{k} W[po, k] * x[b, k] + bias[po]
// M=32 (batch), N=4096 (po), K=16384. Memory-bound on streaming W (256 MB fp32).

#define KDIM 16384   // I0*I1
#define NPO 4096     // O0*O1
#define PO_TILE 8
#define KCHUNK 256   // 64 lanes * 4 floats
#define NITER 64     // KDIM / KCHUNK

__global__ __launch_bounds__(256, 2)
void trace_kernel(const float* __restrict__ x, const float* __restrict__ w,
                  const float* __restrict__ bias, float* __restrict__ out) {
  const int lane = threadIdx.x & 63;
  const int wave = threadIdx.x >> 6;          // 0..3
  const int po_base = blockIdx.x * PO_TILE;   // 8 po's per block
  const int b0 = wave * 8;                    // 8 batches per wave

  const float* wbase = w + (size_t)po_base * KDIM + (lane << 2);
  const float* xbase = x + (size_t)b0 * KDIM + (lane << 2);

  float acc[8][8];
#pragma unroll
  for (int i = 0; i < 8; ++i)
#pragma unroll
    for (int j = 0; j < 8; ++j) acc[i][j] = 0.f;

  float4 xa[8], wa[8], xb[8], wb[8];

  // prologue: load chunk 0 into A buffers
#pragma unroll
  for (int pp = 0; pp < 8; ++pp)
    wa[pp] = *reinterpret_cast<const float4*>(wbase + (size_t)pp * KDIM);
#pragma unroll
  for (int bb = 0; bb < 8; ++bb)
    xa[bb] = *reinterpret_cast<const float4*>(xbase + (size_t)bb * KDIM);

  for (int it = 0; it < NITER; it += 2) {
    // prefetch chunk it+1 into B (it+1 always < NITER since NITER even)
    {
      const float* wp = wbase + (size_t)(it + 1) * KCHUNK;
      const float* xp = xbase + (size_t)(it + 1) * KCHUNK;
#pragma unroll
      for (int pp = 0; pp < 8; ++pp)
        wb[pp] = *reinterpret_cast<const float4*>(wp + (size_t)pp * KDIM);
#pragma unroll
      for (int bb = 0; bb < 8; ++bb)
        xb[bb] = *reinterpret_cast<const float4*>(xp + (size_t)bb * KDIM);
    }
    // FMA on A
#pragma unroll
    for (int bb = 0; bb < 8; ++bb)
#pragma unroll
      for (int pp = 0; pp < 8; ++pp) {
        acc[bb][pp] += xa[bb].x * wa[pp].x;
        acc[bb][pp] += xa[bb].y * wa[pp].y;
        acc[bb][pp] += xa[bb].z * wa[pp].z;
        acc[bb][pp] += xa[bb].w * wa[pp].w;
      }
    // prefetch chunk it+2 into A
    if (it + 2 < NITER) {
      const float* wp = wbase + (size_t)(it + 2) * KCHUNK;
      const float* xp = xbase + (size_t)(it + 2) * KCHUNK;
#pragma unroll
      for (int pp = 0; pp < 8; ++pp)
        wa[pp] = *reinterpret_cast<const float4*>(wp + (size_t)pp * KDIM);
#pragma unroll
      for (int bb = 0; bb < 8; ++bb)
        xa[bb] = *reinterpret_cast<const float4*>(xp + (size_t)bb * KDIM);
    }
    // FMA on B
#pragma unroll
    for (int bb = 0; bb < 8; ++bb)
#pragma unroll
      for (int pp = 0; pp < 8; ++pp) {
        acc[bb][pp] += xb[bb].x * wb[pp].x;
        acc[bb][pp] += xb[bb].y * wb[pp].y;
        acc[bb][pp] += xb[bb].z * wb[pp].z;
        acc[bb][pp] += xb[bb].w * wb[pp].w;
      }
  }

  // bias for this lane's output column (load early to hide latency)
  const float bsv = bias[po_base + (lane & 7)];

  // Each lane holds partial sums over its k-slice; lanes partition K.
  // Full 64-lane butterfly per element, then lane e keeps element e.
  const float* accf = &acc[0][0];
  float val = 0.f;
#pragma unroll
  for (int e = 0; e < 64; ++e) {
    float v = accf[e];
    v += __shfl_xor(v, 1);
    v += __shfl_xor(v, 2);
    v += __shfl_xor(v, 4);
    v += __shfl_xor(v, 8);
    v += __shfl_xor(v, 16);
    v += __shfl_xor(v, 32);
    val = (lane == e) ? v : val;
  }

  // element e = bb*8 + pp  ->  lane l writes (b0 + l>>3, po_base + (l&7))
  out[(size_t)(b0 + (lane >> 3)) * NPO + po_base + (lane & 7)] = val + bsv;
}

extern "C" void kernel_launch(void* const* d_in, const int* in_sizes, int n_in,
                              void* d_out, int out_size, void* d_ws, size_t ws_size,
                              hipStream_t stream) {
  const float* x    = (const float*)d_in[0];
  const float* wgt  = (const float*)d_in[1];
  const float* bias = (const float*)d_in[2];
  float* out = (float*)d_out;
  dim3 grid(NPO / PO_TILE);  // 512 blocks
  dim3 block(256);
  hipLaunchKernelGGL(trace_kernel, grid, block, 0, stream, x, wgt, bias, out);
}